// Round 4
// baseline (177.180 us; speedup 1.0000x reference)
//
#include <hip/hip_runtime.h>
#include <stdint.h>

// SWF2LUT 4-simplex interpolation, mode 's'.
// img_in: (8,1,513,513) f32, integer values 0..255
// weight: (17^4, 3) f32  -> quantized clip(round(w*127),-127,127)
// out:    (8,1,512,512,3) f32
//
// ROUND 4 = DISCRIMINATING EXPERIMENT. Rounds 1-3 showed dur_us is a
// constant ~41-43us + (build-kernel cost), invariant to gather structure.
// Either (C) interp itself is ~40us from a shared cost, or (B') the 256MiB
// d_ws poison fill sits in the timed window and interp is ~2-3us
// (L3-resident working set). Here: exact round-1 kernels, interp launched
// 5x (idempotent, deterministic). C predicts ~200us + interp counters in
// top-5; B' predicts ~50us with top-5 still all fills.

#define LQ   17
#define L2C  (17 * 17)        // 289
#define L3C  (17 * 17 * 17)   // 4913
#define NENT (L3C * 17)       // 83521
#define SUMSTRIDE (L3C + L2C + LQ + 1)  // 5220 (constant last cumsum)

// ---- pre-kernel: quantize weight table and pack 3x int8 into one u32 ----
__global__ __launch_bounds__(256) void quant_pack_kernel(
    const float* __restrict__ w, uint32_t* __restrict__ tab, int n) {
    int e = blockIdx.x * 256 + threadIdx.x;
    if (e >= n) return;
    int q0 = (int)rintf(w[e * 3 + 0] * 127.0f);
    int q1 = (int)rintf(w[e * 3 + 1] * 127.0f);
    int q2 = (int)rintf(w[e * 3 + 2] * 127.0f);
    q0 = min(127, max(-127, q0));
    q1 = min(127, max(-127, q1));
    q2 = min(127, max(-127, q2));
    tab[e] = (uint32_t)(q0 & 0xFF) | ((uint32_t)(q1 & 0xFF) << 8) |
             ((uint32_t)(q2 & 0xFF) << 16);
}

__device__ __forceinline__ int stride_of(int j) {
    // strides[j] = 17^(3-j); cndmask chain, no runtime-indexed array
    return j == 0 ? L3C : (j == 1 ? L2C : (j == 2 ? LQ : 1));
}

// ---- main kernel (packed int8 table in d_ws) ----
// One thread = 4 consecutive x pixels. 8*512*128 = 524288 threads.
__global__ __launch_bounds__(256) void interp_packed_kernel(
    const float* __restrict__ img, const uint32_t* __restrict__ tab,
    float* __restrict__ out) {
    int gid = blockIdx.x * 256 + threadIdx.x;   // 0..524287
    int x0 = (gid & 127) << 2;                  // 0..508 step 4
    int y  = (gid >> 7) & 511;
    int im = gid >> 16;                         // 0..7

    const float* r0 = img + im * (513 * 513) + y * 513 + x0;
    const float* r1 = r0 + 513;
    float v0[5], v1[5];
#pragma unroll
    for (int i = 0; i < 5; ++i) { v0[i] = r0[i]; v1[i] = r1[i]; }

    float res[12];
#pragma unroll
    for (int i = 0; i < 4; ++i) {
        int a = (int)v0[i], b = (int)v0[i + 1];
        int c = (int)v1[i], d = (int)v1[i + 1];
        int base = (a >> 4) * L3C + (b >> 4) * L2C + (c >> 4) * LQ + (d >> 4);
        // keys: f*4 + coord_index  (distinct; replicates argsort(-tie_key))
        int k0 = ((a & 15) << 2) | 0;
        int k1 = ((b & 15) << 2) | 1;
        int k2 = ((c & 15) << 2) | 2;
        int k3 = ((d & 15) << 2) | 3;
        int t;
        if (k0 < k1) { t = k0; k0 = k1; k1 = t; }
        if (k2 < k3) { t = k2; k2 = k3; k3 = t; }
        if (k0 < k2) { t = k0; k0 = k2; k2 = t; }
        if (k1 < k3) { t = k1; k1 = k3; k3 = t; }
        if (k1 < k2) { t = k1; k1 = k2; k2 = t; }
        int fs0 = k0 >> 2, fs1 = k1 >> 2, fs2 = k2 >> 2, fs3 = k3 >> 2;
        int s0 = stride_of(k0 & 3);
        int s1 = stride_of(k1 & 3);
        int s2 = stride_of(k2 & 3);
        int i0 = base;
        int i1 = base + s0;
        int i2 = i1 + s1;
        int i3 = i2 + s2;
        int i4 = base + SUMSTRIDE;   // cumsum of all 4 strides is constant
        uint32_t u0 = tab[i0], u1 = tab[i1], u2 = tab[i2], u3 = tab[i3],
                 u4 = tab[i4];
        int w0 = 16 - fs0, w1 = fs0 - fs1, w2 = fs1 - fs2, w3 = fs2 - fs3,
            w4 = fs3;
#pragma unroll
        for (int ch = 0; ch < 3; ++ch) {
            int sh = 24 - ch * 8;
            int p0 = (int)(u0 << sh) >> 24;
            int p1 = (int)(u1 << sh) >> 24;
            int p2 = (int)(u2 << sh) >> 24;
            int p3 = (int)(u3 << sh) >> 24;
            int p4 = (int)(u4 << sh) >> 24;
            int acc = w0 * p0 + w1 * p1 + w2 * p2 + w3 * p3 + w4 * p4;
            res[i * 3 + ch] = (float)acc * 0.0625f;  // /16 exact
        }
    }

    int opix = ((im * 512 + y) * 512 + x0) * 3;  // multiple of 12 -> 48B aligned
    float4* o = (float4*)(out + opix);
    o[0] = make_float4(res[0], res[1], res[2], res[3]);
    o[1] = make_float4(res[4], res[5], res[6], res[7]);
    o[2] = make_float4(res[8], res[9], res[10], res[11]);
}

// ---- fallback: gather f32 weights, quantize inline (if ws too small) ----
__device__ __forceinline__ float quant1(float x) {
    return fminf(127.0f, fmaxf(-127.0f, rintf(x * 127.0f)));
}

__global__ __launch_bounds__(256) void interp_float_kernel(
    const float* __restrict__ img, const float* __restrict__ wgt,
    float* __restrict__ out) {
    int gid = blockIdx.x * 256 + threadIdx.x;
    int x0 = (gid & 127) << 2;
    int y  = (gid >> 7) & 511;
    int im = gid >> 16;

    const float* r0 = img + im * (513 * 513) + y * 513 + x0;
    const float* r1 = r0 + 513;
    float v0[5], v1[5];
#pragma unroll
    for (int i = 0; i < 5; ++i) { v0[i] = r0[i]; v1[i] = r1[i]; }

    float res[12];
#pragma unroll
    for (int i = 0; i < 4; ++i) {
        int a = (int)v0[i], b = (int)v0[i + 1];
        int c = (int)v1[i], d = (int)v1[i + 1];
        int base = (a >> 4) * L3C + (b >> 4) * L2C + (c >> 4) * LQ + (d >> 4);
        int k0 = ((a & 15) << 2) | 0;
        int k1 = ((b & 15) << 2) | 1;
        int k2 = ((c & 15) << 2) | 2;
        int k3 = ((d & 15) << 2) | 3;
        int t;
        if (k0 < k1) { t = k0; k0 = k1; k1 = t; }
        if (k2 < k3) { t = k2; k2 = k3; k3 = t; }
        if (k0 < k2) { t = k0; k0 = k2; k2 = t; }
        if (k1 < k3) { t = k1; k1 = k3; k3 = t; }
        if (k1 < k2) { t = k1; k1 = k2; k2 = t; }
        int fs0 = k0 >> 2, fs1 = k1 >> 2, fs2 = k2 >> 2, fs3 = k3 >> 2;
        int s0 = stride_of(k0 & 3);
        int s1 = stride_of(k1 & 3);
        int s2 = stride_of(k2 & 3);
        int i0 = base;
        int i1 = base + s0;
        int i2 = i1 + s1;
        int i3 = i2 + s2;
        int i4 = base + SUMSTRIDE;
        float w0 = (float)(16 - fs0), w1 = (float)(fs0 - fs1),
              w2 = (float)(fs1 - fs2), w3 = (float)(fs2 - fs3),
              w4 = (float)fs3;
#pragma unroll
        for (int ch = 0; ch < 3; ++ch) {
            float p0 = quant1(wgt[i0 * 3 + ch]);
            float p1 = quant1(wgt[i1 * 3 + ch]);
            float p2 = quant1(wgt[i2 * 3 + ch]);
            float p3 = quant1(wgt[i3 * 3 + ch]);
            float p4 = quant1(wgt[i4 * 3 + ch]);
            float acc = w0 * p0 + w1 * p1 + w2 * p2 + w3 * p3 + w4 * p4;
            res[i * 3 + ch] = acc * 0.0625f;
        }
    }

    int opix = ((im * 512 + y) * 512 + x0) * 3;
    float4* o = (float4*)(out + opix);
    o[0] = make_float4(res[0], res[1], res[2], res[3]);
    o[1] = make_float4(res[4], res[5], res[6], res[7]);
    o[2] = make_float4(res[8], res[9], res[10], res[11]);
}

extern "C" void kernel_launch(void* const* d_in, const int* in_sizes, int n_in,
                              void* d_out, int out_size, void* d_ws,
                              size_t ws_size, hipStream_t stream) {
    const float* img = (const float*)d_in[0];
    const float* wgt = (const float*)d_in[1];
    float* out = (float*)d_out;

    const int n_groups = 8 * 512 * 128;      // 524288 threads, 4 px each
    const int grid = n_groups / 256;         // 2048 blocks

    if (ws_size >= (size_t)NENT * sizeof(uint32_t) && d_ws != nullptr) {
        uint32_t* tab = (uint32_t*)d_ws;
        quant_pack_kernel<<<(NENT + 255) / 256, 256, 0, stream>>>(wgt, tab,
                                                                  NENT);
        // Diagnostic: 5 identical idempotent launches. Same work and same
        // output every kernel_launch call; separates interp cost (scales 5x)
        // from any constant timed-window overhead (doesn't scale).
        for (int rep = 0; rep < 5; ++rep) {
            interp_packed_kernel<<<grid, 256, 0, stream>>>(img, tab, out);
        }
    } else {
        interp_float_kernel<<<grid, 256, 0, stream>>>(img, wgt, out);
    }
}

// Round 5
// 62.203 us; speedup vs baseline: 2.8484x; 2.8484x over previous
//
#include <hip/hip_runtime.h>
#include <stdint.h>

// SWF2LUT 4-simplex interpolation, mode 's'.
// img_in: (8,1,513,513) f32, integer values 0..255
// weight: (17^4, 3) f32  -> quantized clip(round(w*127),-127,127)
// out:    (8,1,512,512,3) f32
//
// Round-5 structure, from the round-4 calibration (interp=33.5us, O+Q=9.9us):
// interp is bound by DIVERGENT GATHER instruction-lanes (~2cyc per distinct
// line per lane in L1/TA). So: interp does exactly ONE 16B gather per pixel
// from a [perm][cell] table of 24 perms x 16^4 cells x 16B = 24 MiB holding
// all 5 simplex taps x 3 channels as int8 (validated bit-exact in round 3).
// The table build is two-stage and fully parallel (round 3's mistake was a
// 4-wave/CU latency-bound build): quant_pack (334 KB u32 table), then
// expand_perm with one thread per (perm,cell) -> coalesced reads + stores.

#define LQ   17
#define L2C  (17 * 17)        // 289
#define L3C  (17 * 17 * 17)   // 4913
#define NENT (L3C * 17)       // 83521
#define NCELL 65536           // 16^4 cells
#define NPERM 24
#define SUMSTRIDE (L3C + L2C + LQ + 1)  // 5220 (constant full-path offset)
#define TAB_BYTES ((size_t)NPERM * NCELL * 16)   // 24 MiB

// sign-extend byte k (0..3) of word W
#define SX(W, k) ((int)((W) << (24 - 8 * (k))) >> 24)

// ---- stage 1: quantize weight table, pack 3x int8 into one u32 ----
__global__ __launch_bounds__(256) void quant_pack_kernel(
    const float* __restrict__ w, uint32_t* __restrict__ tab8, int n) {
    int e = blockIdx.x * 256 + threadIdx.x;
    if (e >= n) return;
    int q0 = (int)rintf(w[e * 3 + 0] * 127.0f);   // round-half-even == jnp.round
    int q1 = (int)rintf(w[e * 3 + 1] * 127.0f);
    int q2 = (int)rintf(w[e * 3 + 2] * 127.0f);
    q0 = min(127, max(-127, q0));
    q1 = min(127, max(-127, q1));
    q2 = min(127, max(-127, q2));
    tab8[e] = (uint32_t)(q0 & 0xFF) | ((uint32_t)(q1 & 0xFF) << 8) |
              ((uint32_t)(q2 & 0xFF) << 16);
}

__device__ __forceinline__ int corner_off(int c) {
    // corner code bit3->a+1, bit2->b+1, bit1->c+1, bit0->d+1 in the 17-grid
    return ((c >> 3) & 1) * L3C + ((c >> 2) & 1) * L2C +
           ((c >> 1) & 1) * LQ + (c & 1);
}

// ---- stage 2: expand into [perm][cell] 16B simplex entries ----
// One thread per entry; perm is wave-uniform (NCELL % blockDim == 0), cell
// consecutive across lanes -> all 5 reads coalesced, store coalesced.
__global__ __launch_bounds__(256) void expand_perm_kernel(
    const uint32_t* __restrict__ tab8, uint4* __restrict__ tab) {
    int e = blockIdx.x * 256 + threadIdx.x;   // 0 .. NPERM*NCELL-1
    int perm = e >> 16;                       // wave-uniform
    int cell = e & 0xFFFF;
    // Lehmer decode perm -> axis order (a0,a1,a2)
    int l0 = perm / 6, r = perm - l0 * 6, l1 = r >> 1, l2 = r & 1;
    int a0 = l0;
    int r0 = (a0 == 0) ? 1 : 0;
    int r1 = (a0 <= 1) ? 2 : 1;
    int r2 = (a0 <= 2) ? 3 : 2;
    int a1 = (l1 == 0) ? r0 : ((l1 == 1) ? r1 : r2);
    int s0 = (l1 == 0) ? r1 : r0;
    int s1 = (l1 <= 1) ? r2 : r1;
    int a2 = l2 ? s1 : s0;
    int c1 = 8 >> a0;
    int c2 = c1 | (8 >> a1);
    int c3 = c2 | (8 >> a2);

    int ia = (cell >> 12) & 15, ib = (cell >> 8) & 15;
    int ic = (cell >> 4) & 15,  id = cell & 15;
    int base = ia * L3C + ib * L2C + ic * LQ + id;

    uint32_t t0 = tab8[base];
    uint32_t t1 = tab8[base + corner_off(c1)];
    uint32_t t2 = tab8[base + corner_off(c2)];
    uint32_t t3 = tab8[base + corner_off(c3)];
    uint32_t t4 = tab8[base + SUMSTRIDE];
    uint4 u;
    u.x = t0 | (t1 << 24);           // t0.c0 t0.c1 t0.c2 | t1.c0
    u.y = (t1 >> 8) | (t2 << 16);    // t1.c1 t1.c2 | t2.c0 t2.c1
    u.z = (t2 >> 16) | (t3 << 8);    // t2.c2 | t3.c0 t3.c1 t3.c2
    u.w = t4;                        // t4.c0 t4.c1 t4.c2
    tab[e] = u;
}

// ---- main kernel: one thread = 4 consecutive x pixels, 1 gather/pixel ----
__global__ __launch_bounds__(256) void interp_perm_kernel(
    const float* __restrict__ img, const uint4* __restrict__ tab,
    float* __restrict__ out) {
    int gid = blockIdx.x * 256 + threadIdx.x;   // 0..524287
    int x0 = (gid & 127) << 2;                  // 0..508 step 4
    int y  = (gid >> 7) & 511;
    int im = gid >> 16;                         // 0..7

    const float* r0 = img + im * (513 * 513) + y * 513 + x0;
    const float* r1 = r0 + 513;
    float v0[5], v1[5];
#pragma unroll
    for (int i = 0; i < 5; ++i) { v0[i] = r0[i]; v1[i] = r1[i]; }

    float res[12];
#pragma unroll
    for (int i = 0; i < 4; ++i) {
        int a = (int)v0[i], b = (int)v0[i + 1];
        int c = (int)v1[i], d = (int)v1[i + 1];
        int cell = ((a & 0xF0) << 8) | ((b & 0xF0) << 4) |
                   (c & 0xF0) | (d >> 4);
        // keys: f*4 + coord_index (distinct; replicates argsort(-tie_key))
        int k0 = ((a & 15) << 2) | 0;
        int k1 = ((b & 15) << 2) | 1;
        int k2 = ((c & 15) << 2) | 2;
        int k3 = ((d & 15) << 2) | 3;
        int t;
        if (k0 < k1) { t = k0; k0 = k1; k1 = t; }
        if (k2 < k3) { t = k2; k2 = k3; k3 = t; }
        if (k0 < k2) { t = k0; k0 = k2; k2 = t; }
        if (k1 < k3) { t = k1; k1 = k3; k3 = t; }
        if (k1 < k2) { t = k1; k1 = k2; k2 = t; }
        int fs0 = k0 >> 2, fs1 = k1 >> 2, fs2 = k2 >> 2, fs3 = k3 >> 2;
        // Lehmer encode of the axis sequence -> perm id (matches build)
        int a0 = k0 & 3, a1 = k1 & 3, a2 = k2 & 3, a3 = k3 & 3;
        int l1 = a1 - (a1 > a0 ? 1 : 0);
        int l2 = (a2 > a3) ? 1 : 0;
        int perm = a0 * 6 + l1 * 2 + l2;

        uint4 u = tab[((size_t)perm << 16) | cell];  // ONE gather per pixel

        int w0 = 16 - fs0, w1 = fs0 - fs1, w2 = fs1 - fs2, w3 = fs2 - fs3,
            w4 = fs3;
        // byte m = tap*3 + ch
        int acc0 = w0 * SX(u.x, 0) + w1 * SX(u.x, 3) + w2 * SX(u.y, 2) +
                   w3 * SX(u.z, 1) + w4 * SX(u.w, 0);
        int acc1 = w0 * SX(u.x, 1) + w1 * SX(u.y, 0) + w2 * SX(u.y, 3) +
                   w3 * SX(u.z, 2) + w4 * SX(u.w, 1);
        int acc2 = w0 * SX(u.x, 2) + w1 * SX(u.y, 1) + w2 * SX(u.z, 0) +
                   w3 * SX(u.z, 3) + w4 * SX(u.w, 2);
        res[i * 3 + 0] = (float)acc0 * 0.0625f;  // /16 exact
        res[i * 3 + 1] = (float)acc1 * 0.0625f;
        res[i * 3 + 2] = (float)acc2 * 0.0625f;
    }

    int opix = ((im * 512 + y) * 512 + x0) * 3;  // multiple of 12 -> 48B aligned
    float4* o = (float4*)(out + opix);
    o[0] = make_float4(res[0], res[1], res[2], res[3]);
    o[1] = make_float4(res[4], res[5], res[6], res[7]);
    o[2] = make_float4(res[8], res[9], res[10], res[11]);
}

// ---- fallback: gather f32 weights, quantize inline (if ws too small) ----
__device__ __forceinline__ float quant1(float x) {
    return fminf(127.0f, fmaxf(-127.0f, rintf(x * 127.0f)));
}

__device__ __forceinline__ int stride_of(int j) {
    return j == 0 ? L3C : (j == 1 ? L2C : (j == 2 ? LQ : 1));
}

__global__ __launch_bounds__(256) void interp_float_kernel(
    const float* __restrict__ img, const float* __restrict__ wgt,
    float* __restrict__ out) {
    int gid = blockIdx.x * 256 + threadIdx.x;
    int x0 = (gid & 127) << 2;
    int y  = (gid >> 7) & 511;
    int im = gid >> 16;

    const float* r0 = img + im * (513 * 513) + y * 513 + x0;
    const float* r1 = r0 + 513;
    float v0[5], v1[5];
#pragma unroll
    for (int i = 0; i < 5; ++i) { v0[i] = r0[i]; v1[i] = r1[i]; }

    float res[12];
#pragma unroll
    for (int i = 0; i < 4; ++i) {
        int a = (int)v0[i], b = (int)v0[i + 1];
        int c = (int)v1[i], d = (int)v1[i + 1];
        int base = (a >> 4) * L3C + (b >> 4) * L2C + (c >> 4) * LQ + (d >> 4);
        int k0 = ((a & 15) << 2) | 0;
        int k1 = ((b & 15) << 2) | 1;
        int k2 = ((c & 15) << 2) | 2;
        int k3 = ((d & 15) << 2) | 3;
        int t;
        if (k0 < k1) { t = k0; k0 = k1; k1 = t; }
        if (k2 < k3) { t = k2; k2 = k3; k3 = t; }
        if (k0 < k2) { t = k0; k0 = k2; k2 = t; }
        if (k1 < k3) { t = k1; k1 = k3; k3 = t; }
        if (k1 < k2) { t = k1; k1 = k2; k2 = t; }
        int fs0 = k0 >> 2, fs1 = k1 >> 2, fs2 = k2 >> 2, fs3 = k3 >> 2;
        int s0 = stride_of(k0 & 3);
        int s1 = stride_of(k1 & 3);
        int s2 = stride_of(k2 & 3);
        int i0 = base;
        int i1 = base + s0;
        int i2 = i1 + s1;
        int i3 = i2 + s2;
        int i4 = base + SUMSTRIDE;
        float w0 = (float)(16 - fs0), w1 = (float)(fs0 - fs1),
              w2 = (float)(fs1 - fs2), w3 = (float)(fs2 - fs3),
              w4 = (float)fs3;
#pragma unroll
        for (int ch = 0; ch < 3; ++ch) {
            float p0 = quant1(wgt[i0 * 3 + ch]);
            float p1 = quant1(wgt[i1 * 3 + ch]);
            float p2 = quant1(wgt[i2 * 3 + ch]);
            float p3 = quant1(wgt[i3 * 3 + ch]);
            float p4 = quant1(wgt[i4 * 3 + ch]);
            float acc = w0 * p0 + w1 * p1 + w2 * p2 + w3 * p3 + w4 * p4;
            res[i * 3 + ch] = acc * 0.0625f;
        }
    }

    int opix = ((im * 512 + y) * 512 + x0) * 3;
    float4* o = (float4*)(out + opix);
    o[0] = make_float4(res[0], res[1], res[2], res[3]);
    o[1] = make_float4(res[4], res[5], res[6], res[7]);
    o[2] = make_float4(res[8], res[9], res[10], res[11]);
}

extern "C" void kernel_launch(void* const* d_in, const int* in_sizes, int n_in,
                              void* d_out, int out_size, void* d_ws,
                              size_t ws_size, hipStream_t stream) {
    const float* img = (const float*)d_in[0];
    const float* wgt = (const float*)d_in[1];
    float* out = (float*)d_out;

    const int n_groups = 8 * 512 * 128;      // 524288 threads, 4 px each
    const int grid = n_groups / 256;         // 2048 blocks

    const size_t need = TAB_BYTES + (size_t)NENT * sizeof(uint32_t);
    if (ws_size >= need && d_ws != nullptr) {
        uint4* tab = (uint4*)d_ws;                         // 24 MiB
        uint32_t* tab8 = (uint32_t*)((char*)d_ws + TAB_BYTES);  // 334 KB
        quant_pack_kernel<<<(NENT + 255) / 256, 256, 0, stream>>>(wgt, tab8,
                                                                  NENT);
        expand_perm_kernel<<<NPERM * NCELL / 256, 256, 0, stream>>>(tab8, tab);
        interp_perm_kernel<<<grid, 256, 0, stream>>>(img, tab, out);
    } else {
        interp_float_kernel<<<grid, 256, 0, stream>>>(img, wgt, out);
    }
}

// Round 6
// 56.729 us; speedup vs baseline: 3.1233x; 1.0965x over previous
//
#include <hip/hip_runtime.h>
#include <stdint.h>

// SWF2LUT 4-simplex interpolation, mode 's'.
// img_in: (8,1,513,513) f32, integer values 0..255
// weight: (17^4, 3) f32  -> quantized clip(round(w*127),-127,127)
// out:    (8,1,512,512,3) f32
//
// Round-6 model (consistent with rounds 1-5): divergent global gathers cost
// ~2 cyc per distinct 128B segment, serialized per CU (10.5M transactions
// => 34us), and L2-missing gathers add ~128B/px of L3 line traffic (round 5).
// Fix: gather from LDS instead (per-CU LDS pipe, ~9cyc per 64-lane random
// byte-gather wave-instr). Full table (83,506 x 3ch int8 = 245 KiB) exceeds
// 160 KiB LDS, but ONE CHANNEL (81.6 KiB) fits -> 3 x 256 workgroups, each
// stages its channel plane into dynamic LDS and emits that channel only.

#define LQ   17
#define L2C  (17 * 17)        // 289
#define L3C  (17 * 17 * 17)   // 4913
#define NENT (L3C * 17)       // 83521
#define NUSED 83506           // max touched index: base<=78285, +5220 -> 83505
#define PLANE_STRIDE 83584    // padded plane stride (multiple of 16)
#define LDS_BYTES 83584
#define SUMSTRIDE (L3C + L2C + LQ + 1)  // 5220 (constant full-path offset)

__device__ __forceinline__ int stride_of(int j) {
    // strides[j] = 17^(3-j); cndmask chain, no runtime-indexed array
    return j == 0 ? L3C : (j == 1 ? L2C : (j == 2 ? LQ : 1));
}

// ---- stage 1a: quantize weights into 3 channel-planar int8 tables ----
__global__ __launch_bounds__(256) void quant_planar_kernel(
    const float* __restrict__ w, char* __restrict__ planes, int n) {
    int e = blockIdx.x * 256 + threadIdx.x;
    if (e >= n) return;
#pragma unroll
    for (int ch = 0; ch < 3; ++ch) {
        int q = (int)rintf(w[e * 3 + ch] * 127.0f);  // round-half-even
        q = min(127, max(-127, q));
        planes[ch * PLANE_STRIDE + e] = (char)q;
    }
}

// ---- main kernel: LDS-resident single-channel table ----
// grid = 3 channels x 256 parts. Each WG: stage 81.6 KiB plane -> LDS,
// then 8192 px (each thread 8 groups of 4 px), 5 ds_read_i8 per px.
extern __shared__ char lut[];

__global__ __launch_bounds__(256) void interp_lds_kernel(
    const float* __restrict__ img, const char* __restrict__ planes,
    float* __restrict__ out) {
    int wg = blockIdx.x;          // 0..767
    int ch = wg >> 8;             // 0..2
    int part = wg & 255;          // 0..255

    {   // fill LDS with this channel's plane (uint4 copies, coalesced)
        const uint4* src = (const uint4*)(planes + (size_t)ch * PLANE_STRIDE);
        uint4* dst = (uint4*)lut;
#pragma unroll 4
        for (int i = threadIdx.x; i < PLANE_STRIDE / 16; i += 256)
            dst[i] = src[i];
    }
    __syncthreads();
    const signed char* t8 = (const signed char*)lut;

    for (int j = 0; j < 8; ++j) {
        int G = part * 2048 + j * 256 + threadIdx.x;  // group id, 4 px each
        int x0 = (G & 127) << 2;                      // 0..508 step 4
        int y  = (G >> 7) & 511;
        int im = G >> 16;                             // 0..7

        const float* r0 = img + im * (513 * 513) + y * 513 + x0;
        const float* r1 = r0 + 513;
        float v0[5], v1[5];
#pragma unroll
        for (int i = 0; i < 5; ++i) { v0[i] = r0[i]; v1[i] = r1[i]; }

        float res[4];
#pragma unroll
        for (int i = 0; i < 4; ++i) {
            int a = (int)v0[i], b = (int)v0[i + 1];
            int c = (int)v1[i], d = (int)v1[i + 1];
            int base = (a >> 4) * L3C + (b >> 4) * L2C + (c >> 4) * LQ +
                       (d >> 4);
            // keys: f*4 + coord_index (replicates argsort(-tie_key))
            int k0 = ((a & 15) << 2) | 0;
            int k1 = ((b & 15) << 2) | 1;
            int k2 = ((c & 15) << 2) | 2;
            int k3 = ((d & 15) << 2) | 3;
            int t;
            if (k0 < k1) { t = k0; k0 = k1; k1 = t; }
            if (k2 < k3) { t = k2; k2 = k3; k3 = t; }
            if (k0 < k2) { t = k0; k0 = k2; k2 = t; }
            if (k1 < k3) { t = k1; k1 = k3; k3 = t; }
            if (k1 < k2) { t = k1; k1 = k2; k2 = t; }
            int fs0 = k0 >> 2, fs1 = k1 >> 2, fs2 = k2 >> 2, fs3 = k3 >> 2;
            int s0 = stride_of(k0 & 3);
            int s1 = stride_of(k1 & 3);
            int s2 = stride_of(k2 & 3);
            int i0 = base;
            int i1 = i0 + s0;
            int i2 = i1 + s1;
            int i3 = i2 + s2;
            int i4 = base + SUMSTRIDE;
            int p0 = t8[i0];   // ds_read_i8, LDS pipe (no TA serialization)
            int p1 = t8[i1];
            int p2 = t8[i2];
            int p3 = t8[i3];
            int p4 = t8[i4];
            int acc = (16 - fs0) * p0 + (fs0 - fs1) * p1 + (fs1 - fs2) * p2 +
                      (fs2 - fs3) * p3 + fs3 * p4;
            res[i] = (float)acc * 0.0625f;  // /16 exact
        }

        int opix = ((im * 512 + y) * 512 + x0) * 3 + ch;
        out[opix]     = res[0];   // stride-12B stores: ~6 segments/instr, ok
        out[opix + 3] = res[1];
        out[opix + 6] = res[2];
        out[opix + 9] = res[3];
    }
}

// ---- fallback path (round-1, proven 43us): packed u32 table, 5 gathers ----
__global__ __launch_bounds__(256) void quant_pack_kernel(
    const float* __restrict__ w, uint32_t* __restrict__ tab, int n) {
    int e = blockIdx.x * 256 + threadIdx.x;
    if (e >= n) return;
    int q0 = (int)rintf(w[e * 3 + 0] * 127.0f);
    int q1 = (int)rintf(w[e * 3 + 1] * 127.0f);
    int q2 = (int)rintf(w[e * 3 + 2] * 127.0f);
    q0 = min(127, max(-127, q0));
    q1 = min(127, max(-127, q1));
    q2 = min(127, max(-127, q2));
    tab[e] = (uint32_t)(q0 & 0xFF) | ((uint32_t)(q1 & 0xFF) << 8) |
             ((uint32_t)(q2 & 0xFF) << 16);
}

__global__ __launch_bounds__(256) void interp_packed_kernel(
    const float* __restrict__ img, const uint32_t* __restrict__ tab,
    float* __restrict__ out) {
    int gid = blockIdx.x * 256 + threadIdx.x;
    int x0 = (gid & 127) << 2;
    int y  = (gid >> 7) & 511;
    int im = gid >> 16;

    const float* r0 = img + im * (513 * 513) + y * 513 + x0;
    const float* r1 = r0 + 513;
    float v0[5], v1[5];
#pragma unroll
    for (int i = 0; i < 5; ++i) { v0[i] = r0[i]; v1[i] = r1[i]; }

    float res[12];
#pragma unroll
    for (int i = 0; i < 4; ++i) {
        int a = (int)v0[i], b = (int)v0[i + 1];
        int c = (int)v1[i], d = (int)v1[i + 1];
        int base = (a >> 4) * L3C + (b >> 4) * L2C + (c >> 4) * LQ + (d >> 4);
        int k0 = ((a & 15) << 2) | 0;
        int k1 = ((b & 15) << 2) | 1;
        int k2 = ((c & 15) << 2) | 2;
        int k3 = ((d & 15) << 2) | 3;
        int t;
        if (k0 < k1) { t = k0; k0 = k1; k1 = t; }
        if (k2 < k3) { t = k2; k2 = k3; k3 = t; }
        if (k0 < k2) { t = k0; k0 = k2; k2 = t; }
        if (k1 < k3) { t = k1; k1 = k3; k3 = t; }
        if (k1 < k2) { t = k1; k1 = k2; k2 = t; }
        int fs0 = k0 >> 2, fs1 = k1 >> 2, fs2 = k2 >> 2, fs3 = k3 >> 2;
        int s0 = stride_of(k0 & 3);
        int s1 = stride_of(k1 & 3);
        int s2 = stride_of(k2 & 3);
        int i0 = base;
        int i1 = base + s0;
        int i2 = i1 + s1;
        int i3 = i2 + s2;
        int i4 = base + SUMSTRIDE;
        uint32_t u0 = tab[i0], u1 = tab[i1], u2 = tab[i2], u3 = tab[i3],
                 u4 = tab[i4];
        int w0 = 16 - fs0, w1 = fs0 - fs1, w2 = fs1 - fs2, w3 = fs2 - fs3,
            w4 = fs3;
#pragma unroll
        for (int chn = 0; chn < 3; ++chn) {
            int sh = 24 - chn * 8;
            int p0 = (int)(u0 << sh) >> 24;
            int p1 = (int)(u1 << sh) >> 24;
            int p2 = (int)(u2 << sh) >> 24;
            int p3 = (int)(u3 << sh) >> 24;
            int p4 = (int)(u4 << sh) >> 24;
            int acc = w0 * p0 + w1 * p1 + w2 * p2 + w3 * p3 + w4 * p4;
            res[i * 3 + chn] = (float)acc * 0.0625f;
        }
    }

    int opix = ((im * 512 + y) * 512 + x0) * 3;
    float4* o = (float4*)(out + opix);
    o[0] = make_float4(res[0], res[1], res[2], res[3]);
    o[1] = make_float4(res[4], res[5], res[6], res[7]);
    o[2] = make_float4(res[8], res[9], res[10], res[11]);
}

extern "C" void kernel_launch(void* const* d_in, const int* in_sizes, int n_in,
                              void* d_out, int out_size, void* d_ws,
                              size_t ws_size, hipStream_t stream) {
    const float* img = (const float*)d_in[0];
    const float* wgt = (const float*)d_in[1];
    float* out = (float*)d_out;

    const size_t planes_bytes = (size_t)3 * PLANE_STRIDE;

    // Enable >64KiB dynamic LDS for the interp kernel. Host-side attribute
    // set; idempotent, not a stream op (graph-capture safe). Same result
    // every call -> deterministic branch.
    bool lds_ok = (ws_size >= planes_bytes) && (d_ws != nullptr);
    if (lds_ok) {
        hipError_t e = hipFuncSetAttribute(
            reinterpret_cast<const void*>(interp_lds_kernel),
            hipFuncAttributeMaxDynamicSharedMemorySize, LDS_BYTES);
        lds_ok = (e == hipSuccess);
    }

    if (lds_ok) {
        char* planes = (char*)d_ws;    // 3 x 81.6 KiB int8 channel planes
        quant_planar_kernel<<<(NENT + 255) / 256, 256, 0, stream>>>(
            wgt, planes, NENT);
        interp_lds_kernel<<<768, 256, LDS_BYTES, stream>>>(img, planes, out);
    } else if (ws_size >= (size_t)NENT * sizeof(uint32_t) && d_ws != nullptr) {
        uint32_t* tab = (uint32_t*)d_ws;
        quant_pack_kernel<<<(NENT + 255) / 256, 256, 0, stream>>>(wgt, tab,
                                                                  NENT);
        interp_packed_kernel<<<8 * 512 * 128 / 256, 256, 0, stream>>>(
            img, tab, out);
    }
}

// Round 7
// 44.539 us; speedup vs baseline: 3.9781x; 1.2737x over previous
//
#include <hip/hip_runtime.h>
#include <stdint.h>

// SWF2LUT 4-simplex interpolation, mode 's'.
// img_in: (8,1,513,513) f32, integer values 0..255
// weight: (17^4, 3) f32  -> quantized clip(round(w*127),-127,127)
// out:    (8,1,512,512,3) f32
//
// Round-7: round 6 proved the LDS-gather design but ran at 4 waves/CU
// (83.5 KiB LDS forces 1 WG/CU; 256-thread WG = 4 waves) -> latency-bound,
// Occupancy 9.5%, VALUBusy 21%. Same 1 WG/CU with a 1024-THREAD WG gives
// 16 waves/CU at the same LDS footprint. Work/thread drops 8->2 iters.

#define LQ   17
#define L2C  (17 * 17)        // 289
#define L3C  (17 * 17 * 17)   // 4913
#define NENT (L3C * 17)       // 83521
#define PLANE_STRIDE 83584    // padded plane stride (multiple of 16)
#define LDS_BYTES 83584
#define SUMSTRIDE (L3C + L2C + LQ + 1)  // 5220 (constant full-path offset)

__device__ __forceinline__ int stride_of(int j) {
    // strides[j] = 17^(3-j); cndmask chain, no runtime-indexed array
    return j == 0 ? L3C : (j == 1 ? L2C : (j == 2 ? LQ : 1));
}

// ---- stage 1: quantize weights into 3 channel-planar int8 tables ----
__global__ __launch_bounds__(256) void quant_planar_kernel(
    const float* __restrict__ w, char* __restrict__ planes, int n) {
    int e = blockIdx.x * 256 + threadIdx.x;
    if (e >= n) return;
#pragma unroll
    for (int ch = 0; ch < 3; ++ch) {
        int q = (int)rintf(w[e * 3 + ch] * 127.0f);  // round-half-even
        q = min(127, max(-127, q));
        planes[ch * PLANE_STRIDE + e] = (char)q;
    }
}

// ---- main kernel: LDS-resident single-channel table, 1024-thread WGs ----
// grid = 3 channels x 256 parts. Each WG: stage 81.6 KiB plane -> LDS,
// then 8192 px (each thread 2 groups of 4 px), 5 ds_read_i8 per px.
extern __shared__ char lut[];

__global__ __launch_bounds__(1024) void interp_lds_kernel(
    const float* __restrict__ img, const char* __restrict__ planes,
    float* __restrict__ out) {
    int wg = blockIdx.x;          // 0..767
    int ch = wg >> 8;             // 0..2
    int part = wg & 255;          // 0..255

    {   // fill LDS with this channel's plane (uint4 copies, coalesced)
        const uint4* src = (const uint4*)(planes + (size_t)ch * PLANE_STRIDE);
        uint4* dst = (uint4*)lut;
        for (int i = threadIdx.x; i < PLANE_STRIDE / 16; i += 1024)
            dst[i] = src[i];
    }
    __syncthreads();
    const signed char* t8 = (const signed char*)lut;

#pragma unroll
    for (int j = 0; j < 2; ++j) {
        int G = part * 2048 + j * 1024 + threadIdx.x;  // group id, 4 px each
        int x0 = (G & 127) << 2;                       // 0..508 step 4
        int y  = (G >> 7) & 511;
        int im = G >> 16;                              // 0..7

        const float* r0 = img + im * (513 * 513) + y * 513 + x0;
        const float* r1 = r0 + 513;
        float v0[5], v1[5];
#pragma unroll
        for (int i = 0; i < 5; ++i) { v0[i] = r0[i]; v1[i] = r1[i]; }

        float res[4];
#pragma unroll
        for (int i = 0; i < 4; ++i) {
            int a = (int)v0[i], b = (int)v0[i + 1];
            int c = (int)v1[i], d = (int)v1[i + 1];
            int base = (a >> 4) * L3C + (b >> 4) * L2C + (c >> 4) * LQ +
                       (d >> 4);
            // keys: f*4 + coord_index (replicates argsort(-tie_key))
            int k0 = ((a & 15) << 2) | 0;
            int k1 = ((b & 15) << 2) | 1;
            int k2 = ((c & 15) << 2) | 2;
            int k3 = ((d & 15) << 2) | 3;
            int t;
            if (k0 < k1) { t = k0; k0 = k1; k1 = t; }
            if (k2 < k3) { t = k2; k2 = k3; k3 = t; }
            if (k0 < k2) { t = k0; k0 = k2; k2 = t; }
            if (k1 < k3) { t = k1; k1 = k3; k3 = t; }
            if (k1 < k2) { t = k1; k1 = k2; k2 = t; }
            int fs0 = k0 >> 2, fs1 = k1 >> 2, fs2 = k2 >> 2, fs3 = k3 >> 2;
            int s0 = stride_of(k0 & 3);
            int s1 = stride_of(k1 & 3);
            int s2 = stride_of(k2 & 3);
            int i0 = base;
            int i1 = i0 + s0;
            int i2 = i1 + s1;
            int i3 = i2 + s2;
            int i4 = base + SUMSTRIDE;
            int p0 = t8[i0];   // ds_read_i8, LDS pipe (no TA serialization)
            int p1 = t8[i1];
            int p2 = t8[i2];
            int p3 = t8[i3];
            int p4 = t8[i4];
            int acc = (16 - fs0) * p0 + (fs0 - fs1) * p1 + (fs1 - fs2) * p2 +
                      (fs2 - fs3) * p3 + fs3 * p4;
            res[i] = (float)acc * 0.0625f;  // /16 exact
        }

        int opix = ((im * 512 + y) * 512 + x0) * 3 + ch;
        out[opix]     = res[0];   // stride-12B stores: ~6 segments/instr, ok
        out[opix + 3] = res[1];
        out[opix + 6] = res[2];
        out[opix + 9] = res[3];
    }
}

// ---- fallback path (round-1, proven): packed u32 table, 5 gathers ----
__global__ __launch_bounds__(256) void quant_pack_kernel(
    const float* __restrict__ w, uint32_t* __restrict__ tab, int n) {
    int e = blockIdx.x * 256 + threadIdx.x;
    if (e >= n) return;
    int q0 = (int)rintf(w[e * 3 + 0] * 127.0f);
    int q1 = (int)rintf(w[e * 3 + 1] * 127.0f);
    int q2 = (int)rintf(w[e * 3 + 2] * 127.0f);
    q0 = min(127, max(-127, q0));
    q1 = min(127, max(-127, q1));
    q2 = min(127, max(-127, q2));
    tab[e] = (uint32_t)(q0 & 0xFF) | ((uint32_t)(q1 & 0xFF) << 8) |
             ((uint32_t)(q2 & 0xFF) << 16);
}

__global__ __launch_bounds__(256) void interp_packed_kernel(
    const float* __restrict__ img, const uint32_t* __restrict__ tab,
    float* __restrict__ out) {
    int gid = blockIdx.x * 256 + threadIdx.x;
    int x0 = (gid & 127) << 2;
    int y  = (gid >> 7) & 511;
    int im = gid >> 16;

    const float* r0 = img + im * (513 * 513) + y * 513 + x0;
    const float* r1 = r0 + 513;
    float v0[5], v1[5];
#pragma unroll
    for (int i = 0; i < 5; ++i) { v0[i] = r0[i]; v1[i] = r1[i]; }

    float res[12];
#pragma unroll
    for (int i = 0; i < 4; ++i) {
        int a = (int)v0[i], b = (int)v0[i + 1];
        int c = (int)v1[i], d = (int)v1[i + 1];
        int base = (a >> 4) * L3C + (b >> 4) * L2C + (c >> 4) * LQ + (d >> 4);
        int k0 = ((a & 15) << 2) | 0;
        int k1 = ((b & 15) << 2) | 1;
        int k2 = ((c & 15) << 2) | 2;
        int k3 = ((d & 15) << 2) | 3;
        int t;
        if (k0 < k1) { t = k0; k0 = k1; k1 = t; }
        if (k2 < k3) { t = k2; k2 = k3; k3 = t; }
        if (k0 < k2) { t = k0; k0 = k2; k2 = t; }
        if (k1 < k3) { t = k1; k1 = k3; k3 = t; }
        if (k1 < k2) { t = k1; k1 = k2; k2 = t; }
        int fs0 = k0 >> 2, fs1 = k1 >> 2, fs2 = k2 >> 2, fs3 = k3 >> 2;
        int s0 = stride_of(k0 & 3);
        int s1 = stride_of(k1 & 3);
        int s2 = stride_of(k2 & 3);
        int i0 = base;
        int i1 = base + s0;
        int i2 = i1 + s1;
        int i3 = i2 + s2;
        int i4 = base + SUMSTRIDE;
        uint32_t u0 = tab[i0], u1 = tab[i1], u2 = tab[i2], u3 = tab[i3],
                 u4 = tab[i4];
        int w0 = 16 - fs0, w1 = fs0 - fs1, w2 = fs1 - fs2, w3 = fs2 - fs3,
            w4 = fs3;
#pragma unroll
        for (int chn = 0; chn < 3; ++chn) {
            int sh = 24 - chn * 8;
            int p0 = (int)(u0 << sh) >> 24;
            int p1 = (int)(u1 << sh) >> 24;
            int p2 = (int)(u2 << sh) >> 24;
            int p3 = (int)(u3 << sh) >> 24;
            int p4 = (int)(u4 << sh) >> 24;
            int acc = w0 * p0 + w1 * p1 + w2 * p2 + w3 * p3 + w4 * p4;
            res[i * 3 + chn] = (float)acc * 0.0625f;
        }
    }

    int opix = ((im * 512 + y) * 512 + x0) * 3;
    float4* o = (float4*)(out + opix);
    o[0] = make_float4(res[0], res[1], res[2], res[3]);
    o[1] = make_float4(res[4], res[5], res[6], res[7]);
    o[2] = make_float4(res[8], res[9], res[10], res[11]);
}

extern "C" void kernel_launch(void* const* d_in, const int* in_sizes, int n_in,
                              void* d_out, int out_size, void* d_ws,
                              size_t ws_size, hipStream_t stream) {
    const float* img = (const float*)d_in[0];
    const float* wgt = (const float*)d_in[1];
    float* out = (float*)d_out;

    const size_t planes_bytes = (size_t)3 * PLANE_STRIDE;

    // Enable >64KiB dynamic LDS for the interp kernel. Host-side attribute
    // set; idempotent, not a stream op (graph-capture safe, proven round 6).
    bool lds_ok = (ws_size >= planes_bytes) && (d_ws != nullptr);
    if (lds_ok) {
        hipError_t e = hipFuncSetAttribute(
            reinterpret_cast<const void*>(interp_lds_kernel),
            hipFuncAttributeMaxDynamicSharedMemorySize, LDS_BYTES);
        lds_ok = (e == hipSuccess);
    }

    if (lds_ok) {
        char* planes = (char*)d_ws;    // 3 x 81.6 KiB int8 channel planes
        quant_planar_kernel<<<(NENT + 255) / 256, 256, 0, stream>>>(
            wgt, planes, NENT);
        interp_lds_kernel<<<768, 1024, LDS_BYTES, stream>>>(img, planes, out);
    } else if (ws_size >= (size_t)NENT * sizeof(uint32_t) && d_ws != nullptr) {
        uint32_t* tab = (uint32_t*)d_ws;
        quant_pack_kernel<<<(NENT + 255) / 256, 256, 0, stream>>>(wgt, tab,
                                                                  NENT);
        interp_packed_kernel<<<8 * 512 * 128 / 256, 256, 0, stream>>>(
            img, tab, out);
    }
}

// Round 8
// 36.364 us; speedup vs baseline: 4.8724x; 1.2248x over previous
//
#include <hip/hip_runtime.h>
#include <stdint.h>

// SWF2LUT 4-simplex interpolation, mode 's'.
// img_in: (8,1,513,513) f32, integer values 0..255
// weight: (17^4, 3) f32  -> quantized clip(round(w*127),-127,127)
// out:    (8,1,512,512,3) f32
//
// Round-8: fused persistent-phase kernel. Round 6/7 counters showed the
// 3-channel-WG split triples sort VALU, img loads, and HBM writes
// (WRITE_SIZE 73.7MB = 3x output from stride-12 partial-line stores).
// Here ONE WG owns a pixel tile and loops ch=0,1,2, refilling LDS with each
// 81.6 KiB channel plane; sort state (i0..i3, fs-nibbles) is computed once
// and cached in VGPRs; all 3 channels accumulate in registers; final store
// is 3 coalesced float4 per thread (full 64B lines, output written once).

#define LQ   17
#define L2C  (17 * 17)        // 289
#define L3C  (17 * 17 * 17)   // 4913
#define NENT (L3C * 17)       // 83521
#define PLANE_STRIDE 83584    // padded plane stride (multiple of 16)
#define LDS_BYTES 83584
#define SUMSTRIDE (L3C + L2C + LQ + 1)  // 5220 (constant full-path offset)

__device__ __forceinline__ int stride_of(int j) {
    // strides[j] = 17^(3-j); cndmask chain, no runtime-indexed array
    return j == 0 ? L3C : (j == 1 ? L2C : (j == 2 ? LQ : 1));
}

// ---- stage 1: quantize weights into 3 channel-planar int8 tables ----
__global__ __launch_bounds__(256) void quant_planar_kernel(
    const float* __restrict__ w, char* __restrict__ planes, int n) {
    int e = blockIdx.x * 256 + threadIdx.x;
    if (e >= n) return;
#pragma unroll
    for (int ch = 0; ch < 3; ++ch) {
        int q = (int)rintf(w[e * 3 + ch] * 127.0f);  // round-half-even
        q = min(127, max(-127, q));
        planes[ch * PLANE_STRIDE + e] = (char)q;
    }
}

// ---- main fused kernel: 512 WGs x 1024 threads, 4 px/thread ----
extern __shared__ char lut[];

__global__ __launch_bounds__(1024) void interp_fused_kernel(
    const float* __restrict__ img, const char* __restrict__ planes,
    float* __restrict__ out) {
    int G = blockIdx.x * 1024 + threadIdx.x;   // group id, 4 px each
    int x0 = (G & 127) << 2;                   // 0..508 step 4
    int y  = (G >> 7) & 511;
    int im = G >> 16;                          // 0..7

    // ---- phase 0: img load + sort ONCE per pixel; cache state in VGPRs ----
    const float* r0 = img + im * (513 * 513) + y * 513 + x0;
    const float* r1 = r0 + 513;
    float v0[5], v1[5];
#pragma unroll
    for (int i = 0; i < 5; ++i) { v0[i] = r0[i]; v1[i] = r1[i]; }

    int pi0[4], pi1[4], pi2[4], pi3[4], pfs[4];
#pragma unroll
    for (int i = 0; i < 4; ++i) {
        int a = (int)v0[i], b = (int)v0[i + 1];
        int c = (int)v1[i], d = (int)v1[i + 1];
        int base = (a >> 4) * L3C + (b >> 4) * L2C + (c >> 4) * LQ + (d >> 4);
        // keys: f*4 + coord_index (replicates argsort(-tie_key))
        int k0 = ((a & 15) << 2) | 0;
        int k1 = ((b & 15) << 2) | 1;
        int k2 = ((c & 15) << 2) | 2;
        int k3 = ((d & 15) << 2) | 3;
        int t;
        if (k0 < k1) { t = k0; k0 = k1; k1 = t; }
        if (k2 < k3) { t = k2; k2 = k3; k3 = t; }
        if (k0 < k2) { t = k0; k0 = k2; k2 = t; }
        if (k1 < k3) { t = k1; k1 = k3; k3 = t; }
        if (k1 < k2) { t = k1; k1 = k2; k2 = t; }
        int fs0 = k0 >> 2, fs1 = k1 >> 2, fs2 = k2 >> 2, fs3 = k3 >> 2;
        int s0 = stride_of(k0 & 3);
        int s1 = stride_of(k1 & 3);
        int s2 = stride_of(k2 & 3);
        pi0[i] = base;
        pi1[i] = base + s0;
        pi2[i] = base + s0 + s1;
        pi3[i] = base + s0 + s1 + s2;
        pfs[i] = (fs0 << 12) | (fs1 << 8) | (fs2 << 4) | fs3;
    }

    // ---- phases 1..3: per channel, refill LDS plane, gather + dot ----
    float res[12];
#pragma unroll
    for (int ch = 0; ch < 3; ++ch) {
        __syncthreads();   // prior phase's gathers done before overwrite
        {   // fill LDS with channel plane (coalesced uint4 copies)
            const uint4* src =
                (const uint4*)(planes + (size_t)ch * PLANE_STRIDE);
            uint4* dst = (uint4*)lut;
            for (int k = threadIdx.x; k < PLANE_STRIDE / 16; k += 1024)
                dst[k] = src[k];
        }
        __syncthreads();
        const signed char* t8 = (const signed char*)lut;
#pragma unroll
        for (int i = 0; i < 4; ++i) {
            int fs = pfs[i];
            int fs0 = (fs >> 12) & 15, fs1 = (fs >> 8) & 15;
            int fs2 = (fs >> 4) & 15,  fs3 = fs & 15;
            int p0 = t8[pi0[i]];   // ds_read_i8: LDS pipe, no TA serialization
            int p1 = t8[pi1[i]];
            int p2 = t8[pi2[i]];
            int p3 = t8[pi3[i]];
            int p4 = t8[pi0[i] + SUMSTRIDE];
            int acc = (16 - fs0) * p0 + (fs0 - fs1) * p1 + (fs1 - fs2) * p2 +
                      (fs2 - fs3) * p3 + fs3 * p4;
            res[i * 3 + ch] = (float)acc * 0.0625f;  // /16 exact
        }
    }

    // ---- single coalesced store: full 64B lines, output written once ----
    int opix = ((im * 512 + y) * 512 + x0) * 3;  // multiple of 12 -> 48B align
    float4* o = (float4*)(out + opix);
    o[0] = make_float4(res[0], res[1], res[2], res[3]);
    o[1] = make_float4(res[4], res[5], res[6], res[7]);
    o[2] = make_float4(res[8], res[9], res[10], res[11]);
}

// ---- fallback path (round-1, proven): packed u32 table, 5 gathers ----
__global__ __launch_bounds__(256) void quant_pack_kernel(
    const float* __restrict__ w, uint32_t* __restrict__ tab, int n) {
    int e = blockIdx.x * 256 + threadIdx.x;
    if (e >= n) return;
    int q0 = (int)rintf(w[e * 3 + 0] * 127.0f);
    int q1 = (int)rintf(w[e * 3 + 1] * 127.0f);
    int q2 = (int)rintf(w[e * 3 + 2] * 127.0f);
    q0 = min(127, max(-127, q0));
    q1 = min(127, max(-127, q1));
    q2 = min(127, max(-127, q2));
    tab[e] = (uint32_t)(q0 & 0xFF) | ((uint32_t)(q1 & 0xFF) << 8) |
             ((uint32_t)(q2 & 0xFF) << 16);
}

__global__ __launch_bounds__(256) void interp_packed_kernel(
    const float* __restrict__ img, const uint32_t* __restrict__ tab,
    float* __restrict__ out) {
    int gid = blockIdx.x * 256 + threadIdx.x;
    int x0 = (gid & 127) << 2;
    int y  = (gid >> 7) & 511;
    int im = gid >> 16;

    const float* r0 = img + im * (513 * 513) + y * 513 + x0;
    const float* r1 = r0 + 513;
    float v0[5], v1[5];
#pragma unroll
    for (int i = 0; i < 5; ++i) { v0[i] = r0[i]; v1[i] = r1[i]; }

    float res[12];
#pragma unroll
    for (int i = 0; i < 4; ++i) {
        int a = (int)v0[i], b = (int)v0[i + 1];
        int c = (int)v1[i], d = (int)v1[i + 1];
        int base = (a >> 4) * L3C + (b >> 4) * L2C + (c >> 4) * LQ + (d >> 4);
        int k0 = ((a & 15) << 2) | 0;
        int k1 = ((b & 15) << 2) | 1;
        int k2 = ((c & 15) << 2) | 2;
        int k3 = ((d & 15) << 2) | 3;
        int t;
        if (k0 < k1) { t = k0; k0 = k1; k1 = t; }
        if (k2 < k3) { t = k2; k2 = k3; k3 = t; }
        if (k0 < k2) { t = k0; k0 = k2; k2 = t; }
        if (k1 < k3) { t = k1; k1 = k3; k3 = t; }
        if (k1 < k2) { t = k1; k1 = k2; k2 = t; }
        int fs0 = k0 >> 2, fs1 = k1 >> 2, fs2 = k2 >> 2, fs3 = k3 >> 2;
        int s0 = stride_of(k0 & 3);
        int s1 = stride_of(k1 & 3);
        int s2 = stride_of(k2 & 3);
        int i0 = base;
        int i1 = base + s0;
        int i2 = i1 + s1;
        int i3 = i2 + s2;
        int i4 = base + SUMSTRIDE;
        uint32_t u0 = tab[i0], u1 = tab[i1], u2 = tab[i2], u3 = tab[i3],
                 u4 = tab[i4];
        int w0 = 16 - fs0, w1 = fs0 - fs1, w2 = fs1 - fs2, w3 = fs2 - fs3,
            w4 = fs3;
#pragma unroll
        for (int chn = 0; chn < 3; ++chn) {
            int sh = 24 - chn * 8;
            int p0 = (int)(u0 << sh) >> 24;
            int p1 = (int)(u1 << sh) >> 24;
            int p2 = (int)(u2 << sh) >> 24;
            int p3 = (int)(u3 << sh) >> 24;
            int p4 = (int)(u4 << sh) >> 24;
            int acc = w0 * p0 + w1 * p1 + w2 * p2 + w3 * p3 + w4 * p4;
            res[i * 3 + chn] = (float)acc * 0.0625f;
        }
    }

    int opix = ((im * 512 + y) * 512 + x0) * 3;
    float4* o = (float4*)(out + opix);
    o[0] = make_float4(res[0], res[1], res[2], res[3]);
    o[1] = make_float4(res[4], res[5], res[6], res[7]);
    o[2] = make_float4(res[8], res[9], res[10], res[11]);
}

extern "C" void kernel_launch(void* const* d_in, const int* in_sizes, int n_in,
                              void* d_out, int out_size, void* d_ws,
                              size_t ws_size, hipStream_t stream) {
    const float* img = (const float*)d_in[0];
    const float* wgt = (const float*)d_in[1];
    float* out = (float*)d_out;

    const size_t planes_bytes = (size_t)3 * PLANE_STRIDE;

    // Enable >64KiB dynamic LDS (host-side attribute, graph-capture safe;
    // proven working rounds 6-7 at this exact size).
    bool lds_ok = (ws_size >= planes_bytes) && (d_ws != nullptr);
    if (lds_ok) {
        hipError_t e = hipFuncSetAttribute(
            reinterpret_cast<const void*>(interp_fused_kernel),
            hipFuncAttributeMaxDynamicSharedMemorySize, LDS_BYTES);
        lds_ok = (e == hipSuccess);
    }

    if (lds_ok) {
        char* planes = (char*)d_ws;    // 3 x 81.6 KiB int8 channel planes
        quant_planar_kernel<<<(NENT + 255) / 256, 256, 0, stream>>>(
            wgt, planes, NENT);
        interp_fused_kernel<<<512, 1024, LDS_BYTES, stream>>>(img, planes,
                                                              out);
    } else if (ws_size >= (size_t)NENT * sizeof(uint32_t) && d_ws != nullptr) {
        uint32_t* tab = (uint32_t*)d_ws;
        quant_pack_kernel<<<(NENT + 255) / 256, 256, 0, stream>>>(wgt, tab,
                                                                  NENT);
        interp_packed_kernel<<<8 * 512 * 128 / 256, 256, 0, stream>>>(
            img, tab, out);
    }
}